// Round 3
// baseline (1735.099 us; speedup 1.0000x reference)
//
#include <hip/hip_runtime.h>
#include <cmath>

typedef _Float16 f16;
typedef _Float16 f16x8 __attribute__((ext_vector_type(8)));
typedef _Float16 f16x4 __attribute__((ext_vector_type(4)));
typedef float f32x4 __attribute__((ext_vector_type(4)));

#define EPSF 1e-6f

// ---------------- async global->LDS, 16B per lane ----------------
__device__ __forceinline__ void gload16(const f16* g, f16* l) {
  __builtin_amdgcn_global_load_lds(
      (__attribute__((address_space(1))) void*)g,
      (__attribute__((address_space(3))) void*)l, 16, 0, 0);
}

// ---------------- weight transpose fp32[K,N] -> f16[N,K] ----------------
__global__ void wtr_k(const float* __restrict__ W, f16* __restrict__ WT, int K, int N) {
  __shared__ float t[32][33];
  const int nb = blockIdx.x * 32, kb = blockIdx.y * 32;
  const int tx = threadIdx.x, ty = threadIdx.y;
#pragma unroll
  for (int i = ty; i < 32; i += 8) t[i][tx] = W[(size_t)(kb + i) * N + nb + tx];
  __syncthreads();
#pragma unroll
  for (int i = ty; i < 32; i += 8) WT[(size_t)(nb + i) * K + kb + tx] = (f16)t[tx][i];
}

// ---------------- flat fp32 -> f16 cast ----------------
__global__ void cast_k(const float* __restrict__ W, f16* __restrict__ H) {
  const size_t i = (size_t)blockIdx.x * 256 + threadIdx.x;
  const float4 v = ((const float4*)W)[i];
  f16x4 o;
  o[0] = (f16)v.x; o[1] = (f16)v.y; o[2] = (f16)v.z; o[3] = (f16)v.w;
  ((f16x4*)H)[i] = o;
}

// ---------------- per-(b,sblk,d) partial sum of clipped x^2 ----------------
__global__ void colsq_k(const float* __restrict__ x, float* __restrict__ part) {
  const int d = blockIdx.x * 256 + threadIdx.x;
  const int sb = blockIdx.y;
  const int b = blockIdx.z;
  const float* p = x + ((size_t)b * 4096 + (size_t)sb * 256) * 1024 + d;
  float acc = 0.f;
#pragma unroll 4
  for (int s = 0; s < 256; ++s) {
    float v = p[(size_t)s * 1024];
    v = fminf(fmaxf(v, -10.f), 10.f);
    acc = fmaf(v, v, acc);
  }
  part[((size_t)b * 16 + sb) * 1024 + d] = acc;
}

// ---------------- Gs, Gt -> Gsum, amp per (b,d) ----------------
__global__ void stats_k(const float* __restrict__ part, float* __restrict__ Gsum,
                        float* __restrict__ amp) {
  const int b = blockIdx.x;
  const int t = threadIdx.x;
  __shared__ double red[256];
  float cs[4];
  double tot = 0.0;
#pragma unroll
  for (int i = 0; i < 4; ++i) {
    const int d = t + i * 256;
    double s = 0.0;
    for (int k = 0; k < 16; ++k) s += (double)part[((size_t)b * 16 + k) * 1024 + d];
    cs[i] = (float)s;
    tot += s;
  }
  red[t] = tot;
  __syncthreads();
  for (int st = 128; st > 0; st >>= 1) {
    if (t < st) red[t] += red[t + st];
    __syncthreads();
  }
  const float Gs = fmaxf(sqrtf((float)red[0] + EPSF), EPSF);
#pragma unroll
  for (int i = 0; i < 4; ++i) {
    const int d = t + i * 256;
    const float Gt = fmaxf(sqrtf(cs[i] + EPSF), EPSF);
    const float gs = Gs + Gt;
    Gsum[(b << 10) + d] = gs;
    amp[(b << 10) + d] = sqrtf(gs * gs + EPSF);
  }
}

// ---------------- rowterm[b,d] = amp[b,:]@Wa[:,d] + ba + bp + gate_bias ----------------
__global__ void rowterm_k(const float* __restrict__ amp, const float* __restrict__ Wa,
                          const float* __restrict__ ba, const float* __restrict__ bp,
                          const float* __restrict__ gbias, float* __restrict__ rt) {
  const int b = blockIdx.y;
  const int d = blockIdx.x * 256 + threadIdx.x;
  const float* a = amp + (b << 10);
  double acc = 0.0;
  for (int k = 0; k < 1024; ++k) acc += (double)a[k] * (double)Wa[((size_t)k << 10) + d];
  rt[(b << 10) + d] = (float)acc + ba[d] + bp[d] + gbias[d];
}

// ---------------- combined bias: bc = b2r@We_top + b2i@We_bot + be ----------------
__global__ void bc_k(const float* __restrict__ b2r, const float* __restrict__ b2i,
                     const float* __restrict__ We, const float* __restrict__ be,
                     float* __restrict__ bc) {
  const int n = blockIdx.x * 256 + threadIdx.x;
  double a = 0.0;
  for (int j = 0; j < 1024; ++j) a += (double)b2r[j] * (double)We[(size_t)j * 1024 + n];
  for (int j = 0; j < 1024; ++j)
    a += (double)b2i[j] * (double)We[(size_t)(1024 + j) * 1024 + n];
  bc[n] = (float)a + be[n];
}

// ---------------- ph materialization: two-valued by sign(x) ----------------
__global__ void ph_k(const float* __restrict__ x, f16* __restrict__ ph, float phPos,
                     float phNeg) {
  const size_t i = (size_t)blockIdx.x * 256 + threadIdx.x;
  const float4 v = ((const float4*)x)[i];
  f16x4 o;
  o[0] = (f16)(v.x < 0.f ? phNeg : phPos);
  o[1] = (f16)(v.y < 0.f ? phNeg : phPos);
  o[2] = (f16)(v.z < 0.f ? phNeg : phPos);
  o[3] = (f16)(v.w < 0.f ? phNeg : phPos);
  ((f16x4*)ph)[i] = o;
}

// ---------------- RMSNorm row kernel: f32 in -> f16 out ----------------
__global__ void rms_k(const float* __restrict__ wave, const float* __restrict__ g,
                      f16* __restrict__ o) {
  const size_t row = blockIdx.x;
  const int t = threadIdx.x;
  const float4 v = ((const float4*)(wave + row * 1024))[t];
  float ss = v.x * v.x + v.y * v.y + v.z * v.z + v.w * v.w;
#pragma unroll
  for (int s = 32; s > 0; s >>= 1) ss += __shfl_down(ss, s);
  __shared__ float red[4];
  if ((t & 63) == 0) red[t >> 6] = ss;
  __syncthreads();
  const float tot = red[0] + red[1] + red[2] + red[3];
  const float r = rsqrtf(tot * (1.f / 1024.f) + EPSF);
  const float4 gv = ((const float4*)g)[t];
  f16x4 ov;
  ov[0] = (f16)(v.x * r * gv.x);
  ov[1] = (f16)(v.y * r * gv.y);
  ov[2] = (f16)(v.z * r * gv.z);
  ov[3] = (f16)(v.w * r * gv.w);
  ((f16x4*)(o + row * 1024))[t] = ov;
}

// ---------------- MFMA GEMM: C[R,N] = A[R,K] * BT[N,K]^T, epilogue fused ----------------
// EPI: 0 = +bias -> f32 ; 1 = accumulate into f32 ; 3 = gelu(+bias) -> f16 ;
//      4 = gate epilogue -> gr,gi f16 ; 5 = plain -> f16
// BM: 128 (4 waves of 64x64) or 64 (4 waves of 32x64)
template <int EPI, int BM>
__global__ __launch_bounds__(256) void gemm_k(
    const f16* __restrict__ A, int lda, const f16* __restrict__ BT, int ldb, int K,
    const float* __restrict__ bias, float* __restrict__ outF, f16* __restrict__ outH,
    int ldo, const f16* __restrict__ phm, const float* __restrict__ rowterm,
    const float* __restrict__ Gsum, f16* __restrict__ gr, f16* __restrict__ gi, int r0,
    float ratioNeg, float stNeg) {
  constexpr int MR = BM / 32;  // acc row-frags per wave (4 or 2)
  __shared__ f16 As[2][BM * 32];
  __shared__ f16 Bs[2][4096];
  const int tid = threadIdx.x;
  const int wv = tid >> 6, ln = tid & 63;

  // bx-major flatten, then bijective XCD-chunk swizzle (m204): each XCD gets a
  // contiguous band of row-tiles x all col-tiles -> A panels stay in its L2.
  const int gyd = gridDim.y;
  const int bid = blockIdx.x * gyd + blockIdx.y;
  const int nwg = gridDim.x * gyd;
  const int q = nwg >> 3, rr = nwg & 7;
  const int xcd = bid & 7, idx = bid >> 3;
  const int swz = (xcd < rr ? xcd * (q + 1) : rr * (q + 1) + (xcd - rr) * q) + idx;
  const int bx = swz / gyd, by = swz % gyd;

  const size_t rbase = (size_t)bx * BM;
  const size_t cbase = (size_t)by * 128;

  // staging: wave wv stages 16 rows per gload16; global k-slot pre-swizzled so LDS
  // stays linear but holds data for slot (ln&3)^((row>>1)&3)  [rule 21]
  const int srow = (wv << 4) + (ln >> 2);
  const int ksw = (((ln & 3) ^ ((srow >> 1) & 3)) << 3);
  const f16* gA = A + (rbase + srow) * (size_t)lda + ksw;
  const f16* gB = BT + (cbase + srow) * (size_t)ldb + ksw;

  f32x4 acc[MR][4];
  const f32x4 zero = {0.f, 0.f, 0.f, 0.f};
#pragma unroll
  for (int m = 0; m < MR; ++m)
#pragma unroll
    for (int n = 0; n < 4; ++n) acc[m][n] = zero;

  const int nk = K >> 5;
  auto stage = [&](int buf, size_t ko) {
    f16* la = &As[buf][wv << 9];
    f16* lb = &Bs[buf][wv << 9];
    gload16(gA + ko, la);
    if constexpr (BM == 128) gload16(gA + ko + (size_t)64 * lda, la + 2048);
    gload16(gB + ko, lb);
    gload16(gB + ko + (size_t)64 * ldb, lb + 2048);
  };
  stage(0, 0);
  __syncthreads();

  const int arow = ln & 15;
  // read-side XOR matches staged permutation (row bits 1..2 == arow bits 1..2)
  const int kg = (((ln >> 4) ^ ((arow >> 1) & 3)) << 3);
  const int wr = (wv >> 1) * (BM / 2);
  const int wc = (wv & 1) << 6;

  for (int t = 0; t < nk; ++t) {
    const int cur = t & 1;
    if (t + 1 < nk) stage(cur ^ 1, (size_t)(t + 1) << 5);
    const f16* ap = &As[cur][(wr + arow) * 32 + kg];
    const f16* bp = &Bs[cur][(wc + arow) * 32 + kg];
    f16x8 af[MR], bfr[4];
#pragma unroll
    for (int m = 0; m < MR; ++m) af[m] = *(const f16x8*)(ap + m * 512);
#pragma unroll
    for (int n = 0; n < 4; ++n) bfr[n] = *(const f16x8*)(bp + n * 512);
#pragma unroll
    for (int m = 0; m < MR; ++m)
#pragma unroll
      for (int n = 0; n < 4; ++n)
        acc[m][n] = __builtin_amdgcn_mfma_f32_16x16x32_f16(af[m], bfr[n], acc[m][n], 0, 0, 0);
    __syncthreads();
  }

  // epilogue; C/D layout: col = lane&15, row = (lane>>4)*4 + j
  const int r4 = (ln >> 4) << 2;
  const int c0 = ln & 15;
#pragma unroll
  for (int m = 0; m < MR; ++m) {
#pragma unroll
    for (int n = 0; n < 4; ++n) {
      const size_t col = cbase + wc + n * 16 + c0;
#pragma unroll
      for (int j = 0; j < 4; ++j) {
        const size_t row = rbase + wr + m * 16 + r4 + j;
        const float v = acc[m][n][j];
        if constexpr (EPI == 0) {
          outF[row * (size_t)ldo + col] = v + bias[col];
        } else if constexpr (EPI == 1) {
          outF[row * (size_t)ldo + col] += v;
        } else if constexpr (EPI == 3) {
          const float u = v + bias[col];
          outH[row * (size_t)ldo + col] = (f16)(0.5f * u * (1.f + erff(u * 0.70710678118654752f)));
        } else if constexpr (EPI == 4) {
          const int gb = (int)(((size_t)r0 + row) >> 12);  // S = 4096
          const float pre = v + rowterm[((size_t)gb << 10) + col];
          const float gate = 1.f / (1.f + expf(-pre));
          const float ph = (float)phm[row * 1024 + col];
          const bool neg = ph > 2.f;
          const float gs = Gsum[((size_t)gb << 10) + col];
          const float cr = neg ? gs * ratioNeg : 0.f;
          const float ci = gs * (neg ? stNeg : 1.f);
          gr[row * 1024 + col] = (f16)(cr * gate);
          gi[row * 1024 + col] = (f16)(ci * gate);
        } else {  // EPI == 5
          outH[row * (size_t)ldo + col] = (f16)v;
        }
      }
    }
  }
}

extern "C" void kernel_launch(void* const* d_in, const int* in_sizes, int n_in,
                              void* d_out, int out_size, void* d_ws, size_t ws_size,
                              hipStream_t stream) {
  const float* x     = (const float*)d_in[0];
  const float* Wa    = (const float*)d_in[1];
  const float* ba    = (const float*)d_in[2];
  const float* Wp    = (const float*)d_in[3];
  const float* bp    = (const float*)d_in[4];
  const float* gbias = (const float*)d_in[5];
  const float* w1r   = (const float*)d_in[6];
  const float* b1r   = (const float*)d_in[7];
  const float* w2r   = (const float*)d_in[8];
  const float* b2r   = (const float*)d_in[9];
  const float* w1i   = (const float*)d_in[10];
  const float* b1i   = (const float*)d_in[11];
  const float* w2i   = (const float*)d_in[12];
  const float* b2i   = (const float*)d_in[13];
  const float* We    = (const float*)d_in[14];
  const float* be    = (const float*)d_in[15];
  const float* grms  = (const float*)d_in[16];
  const float* wf1   = (const float*)d_in[17];
  const float* bf1   = (const float*)d_in[18];
  const float* wf2   = (const float*)d_in[19];
  const float* bf2   = (const float*)d_in[20];
  float* out = (float*)d_out;

  char* ws = (char*)d_ws;
  size_t off = 0;
  auto alloc = [&](size_t bytes) -> void* {
    void* p = (void*)(ws + off);
    off += (bytes + 255) & ~(size_t)255;
    return p;
  };

  // persistent across the whole launch
  f16* WpT   = (f16*)alloc((size_t)1024 * 1024 * 2);
  f16* w1rT  = (f16*)alloc((size_t)4096 * 1024 * 2);
  f16* w1iT  = (f16*)alloc((size_t)4096 * 1024 * 2);
  f16* wf1T  = (f16*)alloc((size_t)2048 * 1024 * 2);
  f16* wf2T  = (f16*)alloc((size_t)1024 * 2048 * 2);
  f16* WcT   = (f16*)alloc((size_t)1024 * 8192 * 2);  // [n][c] fused w2@We (r|i halves)
  float* part    = (float*)alloc((size_t)4 * 16 * 1024 * 4);
  float* GsumB   = (float*)alloc((size_t)4 * 1024 * 4);
  float* ampB    = (float*)alloc((size_t)4 * 1024 * 4);
  float* rowterm = (float*)alloc((size_t)4 * 1024 * 4);
  float* bcB     = (float*)alloc((size_t)1024 * 4);
  const size_t staticEnd = off;

  // temporaries for the Wc precompute, overlapping the chunk region (dead before
  // any chunk kernel writes there; stream ordering guarantees sequencing)
  char* tmp = ws + staticEnd;
  f16* WeT  = (f16*)tmp;                                   // [1024][2048], 4 MB
  f16* w2rH = (f16*)(tmp + (size_t)4 * 1024 * 1024);       // f16 cast, 8 MB
  f16* w2iH = (f16*)(tmp + (size_t)12 * 1024 * 1024);      // f16 cast, 8 MB

  {  // weight transposes + f16 casts (grid = (N/32, K/32) for W[K,N])
    dim3 b(32, 8);
    wtr_k<<<dim3(32, 32), b, 0, stream>>>(Wp, WpT, 1024, 1024);
    wtr_k<<<dim3(128, 32), b, 0, stream>>>(w1r, w1rT, 1024, 4096);
    wtr_k<<<dim3(128, 32), b, 0, stream>>>(w1i, w1iT, 1024, 4096);
    wtr_k<<<dim3(64, 32), b, 0, stream>>>(wf1, wf1T, 1024, 2048);
    wtr_k<<<dim3(32, 64), b, 0, stream>>>(wf2, wf2T, 2048, 1024);
    wtr_k<<<dim3(32, 64), b, 0, stream>>>(We, WeT, 2048, 1024);
    cast_k<<<dim3(4096), 256, 0, stream>>>(w2r, w2rH);
    cast_k<<<dim3(4096), 256, 0, stream>>>(w2i, w2iH);
  }

  colsq_k<<<dim3(4, 16, 4), 256, 0, stream>>>(x, part);
  stats_k<<<4, 256, 0, stream>>>(part, GsumB, ampB);
  rowterm_k<<<dim3(4, 4), 256, 0, stream>>>(ampB, Wa, ba, bp, gbias, rowterm);
  bc_k<<<dim3(4), 256, 0, stream>>>(b2r, b2i, We, be, bcB);

  // WcT[n, 0:4096]  = (w2r @ We_top)^T ; WcT[n, 4096:8192] = (w2i @ We_bot)^T
  gemm_k<5, 128><<<dim3(8, 32), 256, 0, stream>>>(WeT, 2048, w2rH, 1024, 1024, nullptr,
      nullptr, WcT, 8192, nullptr, nullptr, nullptr, nullptr, nullptr, 0, 0.f, 0.f);
  gemm_k<5, 128><<<dim3(8, 32), 256, 0, stream>>>(WeT + 1024, 2048, w2iH, 1024, 1024, nullptr,
      nullptr, WcT + 4096, 8192, nullptr, nullptr, nullptr, nullptr, nullptr, 0, 0.f, 0.f);

  // wave_repr collapses: ratio = (x<0 ? -0.99 : 0), sqrt_term = (x<0 ? sqrt(1-.99^2) : 1)
  const float ratioNeg = -0.99f;
  const float stNeg = sqrtf(fmaxf(1.0f - 0.99f * 0.99f, EPSF));
  const float phPos = atan2f(1.0f, 0.0f);
  const float phNeg = atan2f(stNeg, ratioNeg);

  const long Ntok = (long)in_sizes[0] / 1024;  // 16384
  const size_t perRow = 18432;  // ph 2K + gr 2K + gi 2K + h1(half) 8K + wave/h2 4K
  long R = (long)((ws_size > staticEnd ? ws_size - staticEnd : 0) / perRow);
  R &= ~127L;
  if (R > Ntok) R = Ntok;
  if (R < 128) R = 128;

  char* cb = ws + staticEnd;
  f16* phB = (f16*)cb;                               // R x 1024
  f16* grB = (f16*)(cb + (size_t)R * 2048);          // R x 1024
  f16* giB = (f16*)(cb + (size_t)R * 4096);          // R x 1024
  f16* h1B = (f16*)(cb + (size_t)R * 6144);          // R x 4096 (r then i, sequential)
  char* wvB = cb + (size_t)R * 6144 + (size_t)R * 8192;
  float* waveF = (float*)wvB;                        // R x 1024 f32
  f16* h2B = (f16*)wvB;                              // R x 2048 f16 (after waveF dead)
  f16* outB = phB;                                   // reuse after gate consumed ph

  for (long r0 = 0; r0 < Ntok; r0 += R) {
    const long Rc = (Ntok - r0 < R) ? (Ntok - r0) : R;
    const int g128 = (int)(Rc / 128), g64 = (int)(Rc / 64);
    ph_k<<<dim3((int)Rc), 256, 0, stream>>>(x + r0 * 1024, phB, phPos, phNeg);
    // gate: pre = ph@Wp + rowterm; gr/gi = (cr/ci)*sigmoid(pre)
    gemm_k<4, 64><<<dim3(g64, 8), 256, 0, stream>>>(phB, 1024, WpT, 1024, 1024, nullptr,
        nullptr, nullptr, 1024, phB, rowterm, GsumB, grB, giB, (int)r0, ratioNeg, stNeg);
    // real half: up-proj -> gelu -> h1 ; wave = h1 @ Wc_r + bc
    gemm_k<3, 128><<<dim3(g128, 32), 256, 0, stream>>>(grB, 1024, w1rT, 1024, 1024, b1r,
        nullptr, h1B, 4096, nullptr, nullptr, nullptr, nullptr, nullptr, 0, 0.f, 0.f);
    gemm_k<0, 64><<<dim3(g64, 8), 256, 0, stream>>>(h1B, 4096, WcT, 8192, 4096, bcB,
        waveF, nullptr, 1024, nullptr, nullptr, nullptr, nullptr, nullptr, 0, 0.f, 0.f);
    // imag half: up-proj -> gelu -> h1 ; wave += h1 @ Wc_i
    gemm_k<3, 128><<<dim3(g128, 32), 256, 0, stream>>>(giB, 1024, w1iT, 1024, 1024, b1i,
        nullptr, h1B, 4096, nullptr, nullptr, nullptr, nullptr, nullptr, 0, 0.f, 0.f);
    gemm_k<1, 64><<<dim3(g64, 8), 256, 0, stream>>>(h1B, 4096, WcT + 4096, 8192, 4096, nullptr,
        waveF, nullptr, 1024, nullptr, nullptr, nullptr, nullptr, nullptr, 0, 0.f, 0.f);
    rms_k<<<dim3((int)Rc), 256, 0, stream>>>(waveF, grms, outB);
    // block FFN
    gemm_k<3, 128><<<dim3(g128, 16), 256, 0, stream>>>(outB, 1024, wf1T, 1024, 1024, bf1,
        nullptr, h2B, 2048, nullptr, nullptr, nullptr, nullptr, nullptr, 0, 0.f, 0.f);
    gemm_k<0, 64><<<dim3(g64, 8), 256, 0, stream>>>(h2B, 2048, wf2T, 2048, 2048, bf2,
        out + r0 * 1024, nullptr, 1024, nullptr, nullptr, nullptr, nullptr, nullptr, 0, 0.f, 0.f);
  }
}

// Round 4
// 1700.239 us; speedup vs baseline: 1.0205x; 1.0205x over previous
//
#include <hip/hip_runtime.h>
#include <cmath>

typedef _Float16 f16;
typedef _Float16 f16x8 __attribute__((ext_vector_type(8)));
typedef _Float16 f16x4 __attribute__((ext_vector_type(4)));
typedef float f32x4 __attribute__((ext_vector_type(4)));

#define EPSF 1e-6f

// ---------------- async global->LDS, 16B per lane ----------------
__device__ __forceinline__ void gload16(const f16* g, const f16* l) {
  __builtin_amdgcn_global_load_lds(
      (__attribute__((address_space(1))) void*)g,
      (__attribute__((address_space(3))) void*)l, 16, 0, 0);
}

// ---------------- weight transpose fp32[K,N] -> f16[N,K] ----------------
__global__ void wtr_k(const float* __restrict__ W, f16* __restrict__ WT, int K, int N) {
  __shared__ float t[32][33];
  const int nb = blockIdx.x * 32, kb = blockIdx.y * 32;
  const int tx = threadIdx.x, ty = threadIdx.y;
#pragma unroll
  for (int i = ty; i < 32; i += 8) t[i][tx] = W[(size_t)(kb + i) * N + nb + tx];
  __syncthreads();
#pragma unroll
  for (int i = ty; i < 32; i += 8) WT[(size_t)(nb + i) * K + kb + tx] = (f16)t[tx][i];
}

// ---------------- flat fp32 -> f16 cast ----------------
__global__ void cast_k(const float* __restrict__ W, f16* __restrict__ H) {
  const size_t i = (size_t)blockIdx.x * 256 + threadIdx.x;
  const float4 v = ((const float4*)W)[i];
  f16x4 o;
  o[0] = (f16)v.x; o[1] = (f16)v.y; o[2] = (f16)v.z; o[3] = (f16)v.w;
  ((f16x4*)H)[i] = o;
}

// ---------------- per-(b,sblk,d) partial sum of clipped x^2 ----------------
__global__ void colsq_k(const float* __restrict__ x, float* __restrict__ part) {
  const int d = blockIdx.x * 256 + threadIdx.x;
  const int sb = blockIdx.y;
  const int b = blockIdx.z;
  const float* p = x + ((size_t)b * 4096 + (size_t)sb * 256) * 1024 + d;
  float acc = 0.f;
#pragma unroll 4
  for (int s = 0; s < 256; ++s) {
    float v = p[(size_t)s * 1024];
    v = fminf(fmaxf(v, -10.f), 10.f);
    acc = fmaf(v, v, acc);
  }
  part[((size_t)b * 16 + sb) * 1024 + d] = acc;
}

// ---------------- Gs, Gt -> Gsum, amp per (b,d) ----------------
__global__ void stats_k(const float* __restrict__ part, float* __restrict__ Gsum,
                        float* __restrict__ amp) {
  const int b = blockIdx.x;
  const int t = threadIdx.x;
  __shared__ double red[256];
  float cs[4];
  double tot = 0.0;
#pragma unroll
  for (int i = 0; i < 4; ++i) {
    const int d = t + i * 256;
    double s = 0.0;
    for (int k = 0; k < 16; ++k) s += (double)part[((size_t)b * 16 + k) * 1024 + d];
    cs[i] = (float)s;
    tot += s;
  }
  red[t] = tot;
  __syncthreads();
  for (int st = 128; st > 0; st >>= 1) {
    if (t < st) red[t] += red[t + st];
    __syncthreads();
  }
  const float Gs = fmaxf(sqrtf((float)red[0] + EPSF), EPSF);
#pragma unroll
  for (int i = 0; i < 4; ++i) {
    const int d = t + i * 256;
    const float Gt = fmaxf(sqrtf(cs[i] + EPSF), EPSF);
    const float gs = Gs + Gt;
    Gsum[(b << 10) + d] = gs;
    amp[(b << 10) + d] = sqrtf(gs * gs + EPSF);
  }
}

// ---------------- rowterm[b,d] = amp[b,:]@Wa[:,d] + ba + bp + gate_bias ----------------
__global__ void rowterm_k(const float* __restrict__ amp, const float* __restrict__ Wa,
                          const float* __restrict__ ba, const float* __restrict__ bp,
                          const float* __restrict__ gbias, float* __restrict__ rt) {
  const int b = blockIdx.y;
  const int d = blockIdx.x * 256 + threadIdx.x;
  const float* a = amp + (b << 10);
  double acc = 0.0;
  for (int k = 0; k < 1024; ++k) acc += (double)a[k] * (double)Wa[((size_t)k << 10) + d];
  rt[(b << 10) + d] = (float)acc + ba[d] + bp[d] + gbias[d];
}

// ---------------- combined bias: bc = b2r@We_top + b2i@We_bot + be ----------------
__global__ void bc_k(const float* __restrict__ b2r, const float* __restrict__ b2i,
                     const float* __restrict__ We, const float* __restrict__ be,
                     float* __restrict__ bc) {
  const int n = blockIdx.x * 256 + threadIdx.x;
  double a = 0.0;
  for (int j = 0; j < 1024; ++j) a += (double)b2r[j] * (double)We[(size_t)j * 1024 + n];
  for (int j = 0; j < 1024; ++j)
    a += (double)b2i[j] * (double)We[(size_t)(1024 + j) * 1024 + n];
  bc[n] = (float)a + be[n];
}

// ---------------- ph materialization: two-valued by sign(x) ----------------
__global__ void ph_k(const float* __restrict__ x, f16* __restrict__ ph, float phPos,
                     float phNeg) {
  const size_t i = (size_t)blockIdx.x * 256 + threadIdx.x;
  const float4 v = ((const float4*)x)[i];
  f16x4 o;
  o[0] = (f16)(v.x < 0.f ? phNeg : phPos);
  o[1] = (f16)(v.y < 0.f ? phNeg : phPos);
  o[2] = (f16)(v.z < 0.f ? phNeg : phPos);
  o[3] = (f16)(v.w < 0.f ? phNeg : phPos);
  ((f16x4*)ph)[i] = o;
}

// ---------------- RMSNorm row kernel: f32 in -> f16 out ----------------
__global__ void rms_k(const float* __restrict__ wave, const float* __restrict__ g,
                      f16* __restrict__ o) {
  const size_t row = blockIdx.x;
  const int t = threadIdx.x;
  const float4 v = ((const float4*)(wave + row * 1024))[t];
  float ss = v.x * v.x + v.y * v.y + v.z * v.z + v.w * v.w;
#pragma unroll
  for (int s = 32; s > 0; s >>= 1) ss += __shfl_down(ss, s);
  __shared__ float red[4];
  if ((t & 63) == 0) red[t >> 6] = ss;
  __syncthreads();
  const float tot = red[0] + red[1] + red[2] + red[3];
  const float r = rsqrtf(tot * (1.f / 1024.f) + EPSF);
  const float4 gv = ((const float4*)g)[t];
  f16x4 ov;
  ov[0] = (f16)(v.x * r * gv.x);
  ov[1] = (f16)(v.y * r * gv.y);
  ov[2] = (f16)(v.z * r * gv.z);
  ov[3] = (f16)(v.w * r * gv.w);
  ((f16x4*)(o + row * 1024))[t] = ov;
}

// ============ deep-pipelined MFMA GEMM: C[M,N] = A[M,K] * BT[N,K]^T ============
// BM=256, BN=128, BK=64, 512 threads = 8 waves (4M x 2N), 64x64 out per wave.
// Phase = one kk half-tile: 8 ds_read_b128 + stage-3-ahead (3 gload_lds) +
// 16 MFMA + vmcnt(6) + raw s_barrier. LDS per-row slot rotation kills bank
// conflicts (inverse rotation applied to per-lane global source, rule 21).
// EPI: 0 = +bias -> f32 ; 3 = gelu(+bias) -> f16 ; 4 = gate -> gr,gi f16 ;
//      5 = plain -> f16
template <int EPI>
__global__ __launch_bounds__(512, 2) void gemm8_k(
    const f16* __restrict__ A, int lda, const f16* __restrict__ BT, int ldb, int K,
    const float* __restrict__ bias, float* __restrict__ outF, f16* __restrict__ outH,
    int ldo, const f16* __restrict__ phm, const float* __restrict__ rowterm,
    const float* __restrict__ Gsum, f16* __restrict__ gr, f16* __restrict__ gi, int r0,
    float ratioNeg, float stNeg) {
  __shared__ f16 smA[2][2][8192];  // [buf][kk][row*32 + slot*8 + i], rows 0..255
  __shared__ f16 smB[2][2][4096];  // [buf][kk][row*32 + slot*8 + i], rows 0..127
  const int tid = threadIdx.x;
  const int w = tid >> 6, l = tid & 63;

  // bx-major flatten + bijective XCD-chunk swizzle (m204)
  const int gyd = gridDim.y;
  const int bid = blockIdx.x * gyd + blockIdx.y;
  const int nwg = gridDim.x * gyd;
  const int q = nwg >> 3, rr = nwg & 7;
  const int xcd = bid & 7, idx = bid >> 3;
  const int swz = (xcd < rr ? xcd * (q + 1) : rr * (q + 1) + (xcd - rr) * q) + idx;
  const int bx = swz / gyd, by = swz % gyd;
  const size_t rbase = (size_t)bx * 256;
  const size_t cbase = (size_t)by * 128;

  // staging thread map: row = w*16 + (l>>2) (+128 for pass 1), 16B slot = l&3;
  // global source slot inverse-rotated so LDS[row][slot] = global[row][slot - row/2]
  const int srow = w * 16 + (l >> 2);
  const int slin = l & 3;

  const int nk = K >> 6;
  auto stageH = [&](int buf, int kk, int tt) {
    const size_t kb = (size_t)tt * 64 + (size_t)kk * 32;
    {  // A pass 0 (rows 0..127)
      const int row = srow;
      const int ss = (slin - (row >> 1)) & 3;
      gload16(A + (rbase + row) * (size_t)lda + kb + ss * 8, &smA[buf][kk][w << 9]);
    }
    {  // A pass 1 (rows 128..255)
      const int row = srow + 128;
      const int ss = (slin - (row >> 1)) & 3;
      gload16(A + (rbase + row) * (size_t)lda + kb + ss * 8,
              &smA[buf][kk][4096 + (w << 9)]);
    }
    {  // B (rows 0..127)
      const int row = srow;
      const int ss = (slin - (row >> 1)) & 3;
      gload16(BT + (cbase + row) * (size_t)ldb + kb + ss * 8, &smB[buf][kk][w << 9]);
    }
  };

  f32x4 acc[4][4];
  const f32x4 zero = {0.f, 0.f, 0.f, 0.f};
#pragma unroll
  for (int m = 0; m < 4; ++m)
#pragma unroll
    for (int n = 0; n < 4; ++n) acc[m][n] = zero;

  // prologue: H0=(t0,kk0)->b0, H1=(t0,kk1)->b0, H2=(t1,kk0)->b1
  stageH(0, 0, 0);
  stageH(0, 1, 0);
  stageH(1, 0, nk > 1 ? 1 : 0);
  asm volatile("s_waitcnt vmcnt(6)" ::: "memory");
  __builtin_amdgcn_s_barrier();
  asm volatile("" ::: "memory");

  const int fr = l & 15, hi = l >> 4;
  const int wrb = (w >> 1) << 6;  // wave row base (0/64/128/192)
  const int wcb = (w & 1) << 6;   // wave col base (0/64)

  auto phase = [&](int buf, int kk, int sbuf, int skk, int stt) {
    f16x8 af[4], bf[4];
#pragma unroll
    for (int m = 0; m < 4; ++m) {
      const int row = wrb + m * 16 + fr;
      const int sl = (hi + (row >> 1)) & 3;
      af[m] = *(const f16x8*)&smA[buf][kk][row * 32 + sl * 8];
    }
#pragma unroll
    for (int n = 0; n < 4; ++n) {
      const int row = wcb + n * 16 + fr;
      const int sl = (hi + (row >> 1)) & 3;
      bf[n] = *(const f16x8*)&smB[buf][kk][row * 32 + sl * 8];
    }
    stageH(sbuf, skk, stt);  // stage 3 phases ahead (dead region, clamped at tail)
    __builtin_amdgcn_s_setprio(1);
#pragma unroll
    for (int m = 0; m < 4; ++m)
#pragma unroll
      for (int n = 0; n < 4; ++n)
        acc[m][n] = __builtin_amdgcn_mfma_f32_16x16x32_f16(af[m], bf[n], acc[m][n], 0, 0, 0);
    __builtin_amdgcn_s_setprio(0);
    asm volatile("s_waitcnt vmcnt(6)" ::: "memory");
    __builtin_amdgcn_s_barrier();
    asm volatile("" ::: "memory");
  };

  for (int t = 0; t < nk; ++t) {
    const int b = t & 1;
    const int t1 = (t + 1 < nk) ? t + 1 : nk - 1;
    const int t2 = (t + 2 < nk) ? t + 2 : nk - 1;
    phase(b, 0, b ^ 1, 1, t1);  // reads (b,kk0); stages (t+1,kk1) -> b^1
    phase(b, 1, b, 0, t2);      // reads (b,kk1); stages (t+2,kk0) -> b
  }

  // epilogue; C/D layout: col = lane&15, row = (lane>>4)*4 + j
  const int r4 = hi << 2;
#pragma unroll
  for (int m = 0; m < 4; ++m) {
#pragma unroll
    for (int n = 0; n < 4; ++n) {
      const size_t col = cbase + wcb + n * 16 + fr;
#pragma unroll
      for (int j = 0; j < 4; ++j) {
        const size_t row = rbase + wrb + m * 16 + r4 + j;
        const float v = acc[m][n][j];
        if constexpr (EPI == 0) {
          outF[row * (size_t)ldo + col] = v + bias[col];
        } else if constexpr (EPI == 3) {
          const float u = v + bias[col];
          outH[row * (size_t)ldo + col] = (f16)(0.5f * u * (1.f + erff(u * 0.70710678118654752f)));
        } else if constexpr (EPI == 4) {
          const int gb = (int)(((size_t)r0 + row) >> 12);  // S = 4096
          const float pre = v + rowterm[((size_t)gb << 10) + col];
          const float gate = 1.f / (1.f + expf(-pre));
          const float ph = (float)phm[row * 1024 + col];
          const bool neg = ph > 2.f;
          const float gs = Gsum[((size_t)gb << 10) + col];
          const float cr = neg ? gs * ratioNeg : 0.f;
          const float ci = gs * (neg ? stNeg : 1.f);
          gr[row * 1024 + col] = (f16)(cr * gate);
          gi[row * 1024 + col] = (f16)(ci * gate);
        } else {  // EPI == 5
          outH[row * (size_t)ldo + col] = (f16)v;
        }
      }
    }
  }
}

extern "C" void kernel_launch(void* const* d_in, const int* in_sizes, int n_in,
                              void* d_out, int out_size, void* d_ws, size_t ws_size,
                              hipStream_t stream) {
  const float* x     = (const float*)d_in[0];
  const float* Wa    = (const float*)d_in[1];
  const float* ba    = (const float*)d_in[2];
  const float* Wp    = (const float*)d_in[3];
  const float* bp    = (const float*)d_in[4];
  const float* gbias = (const float*)d_in[5];
  const float* w1r   = (const float*)d_in[6];
  const float* b1r   = (const float*)d_in[7];
  const float* w2r   = (const float*)d_in[8];
  const float* b2r   = (const float*)d_in[9];
  const float* w1i   = (const float*)d_in[10];
  const float* b1i   = (const float*)d_in[11];
  const float* w2i   = (const float*)d_in[12];
  const float* b2i   = (const float*)d_in[13];
  const float* We    = (const float*)d_in[14];
  const float* be    = (const float*)d_in[15];
  const float* grms  = (const float*)d_in[16];
  const float* wf1   = (const float*)d_in[17];
  const float* bf1   = (const float*)d_in[18];
  const float* wf2   = (const float*)d_in[19];
  const float* bf2   = (const float*)d_in[20];
  float* out = (float*)d_out;

  char* ws = (char*)d_ws;
  size_t off = 0;
  auto alloc = [&](size_t bytes) -> void* {
    void* p = (void*)(ws + off);
    off += (bytes + 255) & ~(size_t)255;
    return p;
  };

  // persistent across the whole launch
  f16* WpT   = (f16*)alloc((size_t)1024 * 1024 * 2);
  f16* w1rT  = (f16*)alloc((size_t)4096 * 1024 * 2);
  f16* w1iT  = (f16*)alloc((size_t)4096 * 1024 * 2);
  f16* wf1T  = (f16*)alloc((size_t)2048 * 1024 * 2);
  f16* wf2T  = (f16*)alloc((size_t)1024 * 2048 * 2);
  f16* WcT   = (f16*)alloc((size_t)1024 * 8192 * 2);  // [n][c] fused w2@We (r|i halves)
  float* part    = (float*)alloc((size_t)4 * 16 * 1024 * 4);
  float* GsumB   = (float*)alloc((size_t)4 * 1024 * 4);
  float* ampB    = (float*)alloc((size_t)4 * 1024 * 4);
  float* rowterm = (float*)alloc((size_t)4 * 1024 * 4);
  float* bcB     = (float*)alloc((size_t)1024 * 4);
  const size_t staticEnd = off;

  // temporaries for the Wc precompute, overlapping the chunk region (dead before
  // any chunk kernel writes there; stream ordering guarantees sequencing)
  char* tmp = ws + staticEnd;
  f16* WeT  = (f16*)tmp;                                   // [1024][2048], 4 MB
  f16* w2rH = (f16*)(tmp + (size_t)4 * 1024 * 1024);       // f16 cast, 8 MB
  f16* w2iH = (f16*)(tmp + (size_t)12 * 1024 * 1024);      // f16 cast, 8 MB

  {  // weight transposes + f16 casts (grid = (N/32, K/32) for W[K,N])
    dim3 b(32, 8);
    wtr_k<<<dim3(32, 32), b, 0, stream>>>(Wp, WpT, 1024, 1024);
    wtr_k<<<dim3(128, 32), b, 0, stream>>>(w1r, w1rT, 1024, 4096);
    wtr_k<<<dim3(128, 32), b, 0, stream>>>(w1i, w1iT, 1024, 4096);
    wtr_k<<<dim3(64, 32), b, 0, stream>>>(wf1, wf1T, 1024, 2048);
    wtr_k<<<dim3(32, 64), b, 0, stream>>>(wf2, wf2T, 2048, 1024);
    wtr_k<<<dim3(32, 64), b, 0, stream>>>(We, WeT, 2048, 1024);
    cast_k<<<dim3(4096), 256, 0, stream>>>(w2r, w2rH);
    cast_k<<<dim3(4096), 256, 0, stream>>>(w2i, w2iH);
  }

  colsq_k<<<dim3(4, 16, 4), 256, 0, stream>>>(x, part);
  stats_k<<<4, 256, 0, stream>>>(part, GsumB, ampB);
  rowterm_k<<<dim3(4, 4), 256, 0, stream>>>(ampB, Wa, ba, bp, gbias, rowterm);
  bc_k<<<dim3(4), 256, 0, stream>>>(b2r, b2i, We, be, bcB);

  // WcT[n, 0:4096]  = (w2r @ We_top)^T ; WcT[n, 4096:8192] = (w2i @ We_bot)^T
  gemm8_k<5><<<dim3(4, 32), 512, 0, stream>>>(WeT, 2048, w2rH, 1024, 1024, nullptr,
      nullptr, WcT, 8192, nullptr, nullptr, nullptr, nullptr, nullptr, 0, 0.f, 0.f);
  gemm8_k<5><<<dim3(4, 32), 512, 0, stream>>>(WeT + 1024, 2048, w2iH, 1024, 1024, nullptr,
      nullptr, WcT + 4096, 8192, nullptr, nullptr, nullptr, nullptr, nullptr, 0, 0.f, 0.f);

  // wave_repr collapses: ratio = (x<0 ? -0.99 : 0), sqrt_term = (x<0 ? sqrt(1-.99^2) : 1)
  const float ratioNeg = -0.99f;
  const float stNeg = sqrtf(fmaxf(1.0f - 0.99f * 0.99f, EPSF));
  const float phPos = atan2f(1.0f, 0.0f);
  const float phNeg = atan2f(stNeg, ratioNeg);

  const long Ntok = (long)in_sizes[0] / 1024;  // 16384
  const size_t perRow = 26624;  // ph2K + gr2K + gi2K + h1 16K + wave 4K (h2/out overlay)
  long R = (long)((ws_size > staticEnd ? ws_size - staticEnd : 0) / perRow);
  R &= ~255L;
  if (R >= 16384) R = 16384;
  else if (R >= 8192) R = 8192;  // two perfect chunks; N=1024 grids = exactly 256 WGs
  if (R < 256) R = 256;

  char* cb = ws + staticEnd;
  f16* phB = (f16*)cb;                               // R x 1024
  f16* grB = (f16*)(cb + (size_t)R * 2048);          // R x 1024
  f16* giB = (f16*)(cb + (size_t)R * 4096);          // R x 1024
  f16* h1B = (f16*)(cb + (size_t)R * 6144);          // R x 8192 (r|i halves)
  float* waveF = (float*)(cb + (size_t)R * 22528);   // R x 1024 f32
  f16* h2B = grB;                                    // overlay gr+gi (dead after up-projs)
  f16* outB = phB;                                   // overlay ph (dead after gate)

  for (long r0 = 0; r0 < Ntok; r0 += R) {
    const long Rc = (Ntok - r0 < R) ? (Ntok - r0) : R;
    const int g256 = (int)(Rc / 256);
    ph_k<<<dim3((int)Rc), 256, 0, stream>>>(x + r0 * 1024, phB, phPos, phNeg);
    // gate: pre = ph@Wp + rowterm; gr/gi = (cr/ci)*sigmoid(pre)
    gemm8_k<4><<<dim3(g256, 8), 512, 0, stream>>>(phB, 1024, WpT, 1024, 1024, nullptr,
        nullptr, nullptr, 1024, phB, rowterm, GsumB, grB, giB, (int)r0, ratioNeg, stNeg);
    // up-projections -> gelu -> combined h1 [R x 8192]
    gemm8_k<3><<<dim3(g256, 32), 512, 0, stream>>>(grB, 1024, w1rT, 1024, 1024, b1r,
        nullptr, h1B, 8192, nullptr, nullptr, nullptr, nullptr, nullptr, 0, 0.f, 0.f);
    gemm8_k<3><<<dim3(g256, 32), 512, 0, stream>>>(giB, 1024, w1iT, 1024, 1024, b1i,
        nullptr, h1B + 4096, 8192, nullptr, nullptr, nullptr, nullptr, nullptr, 0, 0.f, 0.f);
    // fused down-proj + We: wave = h1 @ WcT^T + bc
    gemm8_k<0><<<dim3(g256, 8), 512, 0, stream>>>(h1B, 8192, WcT, 8192, 8192, bcB,
        waveF, nullptr, 1024, nullptr, nullptr, nullptr, nullptr, nullptr, 0, 0.f, 0.f);
    rms_k<<<dim3((int)Rc), 256, 0, stream>>>(waveF, grms, outB);
    // block FFN
    gemm8_k<3><<<dim3(g256, 16), 512, 0, stream>>>(outB, 1024, wf1T, 1024, 1024, bf1,
        nullptr, h2B, 2048, nullptr, nullptr, nullptr, nullptr, nullptr, 0, 0.f, 0.f);
    gemm8_k<0><<<dim3(g256, 8), 512, 0, stream>>>(h2B, 2048, wf2T, 2048, 2048, bf2,
        out + r0 * 1024, nullptr, 1024, nullptr, nullptr, nullptr, nullptr, nullptr, 0, 0.f, 0.f);
  }
}

// Round 5
// 1676.654 us; speedup vs baseline: 1.0349x; 1.0141x over previous
//
#include <hip/hip_runtime.h>
#include <cmath>

typedef _Float16 f16;
typedef _Float16 f16x8 __attribute__((ext_vector_type(8)));
typedef _Float16 f16x4 __attribute__((ext_vector_type(4)));
typedef float f32x4 __attribute__((ext_vector_type(4)));

#define EPSF 1e-6f

// ---------------- async global->LDS, 16B per lane ----------------
__device__ __forceinline__ void gload16(const f16* g, const f16* l) {
  __builtin_amdgcn_global_load_lds(
      (__attribute__((address_space(1))) void*)g,
      (__attribute__((address_space(3))) void*)l, 16, 0, 0);
}

// ---------------- weight transpose fp32[K,N] -> f16[N,K] ----------------
__global__ void wtr_k(const float* __restrict__ W, f16* __restrict__ WT, int K, int N) {
  __shared__ float t[32][33];
  const int nb = blockIdx.x * 32, kb = blockIdx.y * 32;
  const int tx = threadIdx.x, ty = threadIdx.y;
#pragma unroll
  for (int i = ty; i < 32; i += 8) t[i][tx] = W[(size_t)(kb + i) * N + nb + tx];
  __syncthreads();
#pragma unroll
  for (int i = ty; i < 32; i += 8) WT[(size_t)(nb + i) * K + kb + tx] = (f16)t[tx][i];
}

// ---------------- flat fp32 -> f16 cast ----------------
__global__ void cast_k(const float* __restrict__ W, f16* __restrict__ H) {
  const size_t i = (size_t)blockIdx.x * 256 + threadIdx.x;
  const float4 v = ((const float4*)W)[i];
  f16x4 o;
  o[0] = (f16)v.x; o[1] = (f16)v.y; o[2] = (f16)v.z; o[3] = (f16)v.w;
  ((f16x4*)H)[i] = o;
}

// ---------------- per-(b,sblk,d) partial sum of clipped x^2 ----------------
__global__ void colsq_k(const float* __restrict__ x, float* __restrict__ part) {
  const int d = blockIdx.x * 256 + threadIdx.x;
  const int sb = blockIdx.y;
  const int b = blockIdx.z;
  const float* p = x + ((size_t)b * 4096 + (size_t)sb * 256) * 1024 + d;
  float acc = 0.f;
#pragma unroll 4
  for (int s = 0; s < 256; ++s) {
    float v = p[(size_t)s * 1024];
    v = fminf(fmaxf(v, -10.f), 10.f);
    acc = fmaf(v, v, acc);
  }
  part[((size_t)b * 16 + sb) * 1024 + d] = acc;
}

// ---------------- Gs, Gt -> Gsum, amp per (b,d) ----------------
__global__ void stats_k(const float* __restrict__ part, float* __restrict__ Gsum,
                        float* __restrict__ amp) {
  const int b = blockIdx.x;
  const int t = threadIdx.x;
  __shared__ double red[256];
  float cs[4];
  double tot = 0.0;
#pragma unroll
  for (int i = 0; i < 4; ++i) {
    const int d = t + i * 256;
    double s = 0.0;
    for (int k = 0; k < 16; ++k) s += (double)part[((size_t)b * 16 + k) * 1024 + d];
    cs[i] = (float)s;
    tot += s;
  }
  red[t] = tot;
  __syncthreads();
  for (int st = 128; st > 0; st >>= 1) {
    if (t < st) red[t] += red[t + st];
    __syncthreads();
  }
  const float Gs = fmaxf(sqrtf((float)red[0] + EPSF), EPSF);
#pragma unroll
  for (int i = 0; i < 4; ++i) {
    const int d = t + i * 256;
    const float Gt = fmaxf(sqrtf(cs[i] + EPSF), EPSF);
    const float gs = Gs + Gt;
    Gsum[(b << 10) + d] = gs;
    amp[(b << 10) + d] = sqrtf(gs * gs + EPSF);
  }
}

// ---------------- rowterm[b,d] = amp[b,:]@Wa[:,d] + ba + bp + gate_bias ----------------
__global__ void rowterm_k(const float* __restrict__ amp, const float* __restrict__ Wa,
                          const float* __restrict__ ba, const float* __restrict__ bp,
                          const float* __restrict__ gbias, float* __restrict__ rt) {
  const int b = blockIdx.y;
  const int d = blockIdx.x * 256 + threadIdx.x;
  const float* a = amp + (b << 10);
  double acc = 0.0;
  for (int k = 0; k < 1024; ++k) acc += (double)a[k] * (double)Wa[((size_t)k << 10) + d];
  rt[(b << 10) + d] = (float)acc + ba[d] + bp[d] + gbias[d];
}

// ---------------- combined bias: bc = b2r@We_top + b2i@We_bot + be ----------------
__global__ void bc_k(const float* __restrict__ b2r, const float* __restrict__ b2i,
                     const float* __restrict__ We, const float* __restrict__ be,
                     float* __restrict__ bc) {
  const int n = blockIdx.x * 256 + threadIdx.x;
  double a = 0.0;
  for (int j = 0; j < 1024; ++j) a += (double)b2r[j] * (double)We[(size_t)j * 1024 + n];
  for (int j = 0; j < 1024; ++j)
    a += (double)b2i[j] * (double)We[(size_t)(1024 + j) * 1024 + n];
  bc[n] = (float)a + be[n];
}

// ---------------- ph materialization: two-valued by sign(x) ----------------
__global__ void ph_k(const float* __restrict__ x, f16* __restrict__ ph, float phPos,
                     float phNeg) {
  const size_t i = (size_t)blockIdx.x * 256 + threadIdx.x;
  const float4 v = ((const float4*)x)[i];
  f16x4 o;
  o[0] = (f16)(v.x < 0.f ? phNeg : phPos);
  o[1] = (f16)(v.y < 0.f ? phNeg : phPos);
  o[2] = (f16)(v.z < 0.f ? phNeg : phPos);
  o[3] = (f16)(v.w < 0.f ? phNeg : phPos);
  ((f16x4*)ph)[i] = o;
}

// ---------------- RMSNorm row kernel: f32 in -> f16 out ----------------
__global__ void rms_k(const float* __restrict__ wave, const float* __restrict__ g,
                      f16* __restrict__ o) {
  const size_t row = blockIdx.x;
  const int t = threadIdx.x;
  const float4 v = ((const float4*)(wave + row * 1024))[t];
  float ss = v.x * v.x + v.y * v.y + v.z * v.z + v.w * v.w;
#pragma unroll
  for (int s = 32; s > 0; s >>= 1) ss += __shfl_down(ss, s);
  __shared__ float red[4];
  if ((t & 63) == 0) red[t >> 6] = ss;
  __syncthreads();
  const float tot = red[0] + red[1] + red[2] + red[3];
  const float r = rsqrtf(tot * (1.f / 1024.f) + EPSF);
  const float4 gv = ((const float4*)g)[t];
  f16x4 ov;
  ov[0] = (f16)(v.x * r * gv.x);
  ov[1] = (f16)(v.y * r * gv.y);
  ov[2] = (f16)(v.z * r * gv.z);
  ov[3] = (f16)(v.w * r * gv.w);
  ((f16x4*)(o + row * 1024))[t] = ov;
}

// ======== MFMA GEMM, BM=128 x BN=256, 8 waves (each 64x64 out) ========
// C[M,N] = A[M,K] * BT[N,K]^T.  2-phase dbuf, gload_lds staging, XOR k-slot
// swizzle (conflict-free, rule 21).  ORD: 0 = row-outer (A panel hot),
// 1 = col-outer (B panel hot, big A streamed N/256 times).
// EPI: 0 = +bias -> f32 ; 1 = += -> f32 ; 3 = gelu(+bias) -> f16 ;
//      4 = gate -> gr,gi f16 ; 5 = plain -> f16
template <int EPI, int ORD>
__global__ __launch_bounds__(512, 4) void gemm2_k(
    const f16* __restrict__ A, int lda, const f16* __restrict__ BT, int ldb, int K,
    const float* __restrict__ bias, float* __restrict__ outF, f16* __restrict__ outH,
    int ldo, const f16* __restrict__ phm, const float* __restrict__ rowterm,
    const float* __restrict__ Gsum, f16* __restrict__ gr, f16* __restrict__ gi, int r0,
    float ratioNeg, float stNeg) {
  __shared__ f16 smA[2][4096];  // 128 rows x 32 k
  __shared__ f16 smB[2][8192];  // 256 rows x 32 k
  const int tid = threadIdx.x;
  const int w = tid >> 6, l = tid & 63;

  // flatten + bijective XCD-chunk swizzle (m204)
  const int nrow = gridDim.x, ncol = gridDim.y;
  const int bid = blockIdx.x * ncol + blockIdx.y;
  const int nwg = nrow * ncol;
  const int q = nwg >> 3, rr = nwg & 7;
  const int xcd = bid & 7, idx = bid >> 3;
  const int swz = (xcd < rr ? xcd * (q + 1) : rr * (q + 1) + (xcd - rr) * q) + idx;
  int bx, by;
  if constexpr (ORD == 0) { bx = swz / ncol; by = swz % ncol; }
  else                    { bx = swz % nrow; by = swz / nrow; }
  const size_t rbase = (size_t)bx * 128;
  const size_t cbase = (size_t)by * 256;

  // staging map: thread covers row srow (A) / srow+128p (B), 16B slot l&3;
  // global k-slot XOR-swizzled by row, LDS linear (rule 21)
  const int srow = (w << 4) + (l >> 2);
  const int slot = l & 3;
  const int ssA = ((slot ^ ((srow >> 1) & 3)) << 3);

  f32x4 acc[4][4];
  const f32x4 zero = {0.f, 0.f, 0.f, 0.f};
#pragma unroll
  for (int m = 0; m < 4; ++m)
#pragma unroll
    for (int n = 0; n < 4; ++n) acc[m][n] = zero;

  const f16* gA = A + (rbase + srow) * (size_t)lda + ssA;
  const f16* gB0 = BT + (cbase + srow) * (size_t)ldb + ssA;
  const int srow1 = srow + 128;
  const f16* gB1 = BT + (cbase + srow1) * (size_t)ldb + ((slot ^ ((srow1 >> 1) & 3)) << 3);

  const int nk = K >> 5;
  auto stage = [&](int buf, size_t ko) {
    gload16(gA + ko, &smA[buf][w << 9]);
    gload16(gB0 + ko, &smB[buf][w << 9]);
    gload16(gB1 + ko, &smB[buf][4096 + (w << 9)]);
  };
  stage(0, 0);
  __syncthreads();

  const int arow = l & 15;
  const int kg = (((l >> 4) ^ ((arow >> 1) & 3)) << 3);  // read-side XOR
  const int wr = (w >> 2) << 6;  // 0 / 64
  const int wc = (w & 3) << 6;   // 0 / 64 / 128 / 192

  for (int t = 0; t < nk; ++t) {
    const int cur = t & 1;
    if (t + 1 < nk) stage(cur ^ 1, (size_t)(t + 1) << 5);
    const f16* ap = &smA[cur][(wr + arow) * 32 + kg];
    const f16* bp = &smB[cur][(wc + arow) * 32 + kg];
    f16x8 af[4], bf[4];
#pragma unroll
    for (int m = 0; m < 4; ++m) af[m] = *(const f16x8*)(ap + m * 512);
#pragma unroll
    for (int n = 0; n < 4; ++n) bf[n] = *(const f16x8*)(bp + n * 512);
#pragma unroll
    for (int m = 0; m < 4; ++m)
#pragma unroll
      for (int n = 0; n < 4; ++n)
        acc[m][n] = __builtin_amdgcn_mfma_f32_16x16x32_f16(af[m], bf[n], acc[m][n], 0, 0, 0);
    __syncthreads();
  }

  // epilogue; C/D layout: col = lane&15, row = (lane>>4)*4 + j
  const int r4 = (l >> 4) << 2;
  const int c0 = l & 15;
#pragma unroll
  for (int m = 0; m < 4; ++m) {
#pragma unroll
    for (int n = 0; n < 4; ++n) {
      const size_t col = cbase + wc + n * 16 + c0;
#pragma unroll
      for (int j = 0; j < 4; ++j) {
        const size_t row = rbase + wr + m * 16 + r4 + j;
        const float v = acc[m][n][j];
        if constexpr (EPI == 0) {
          outF[row * (size_t)ldo + col] = v + bias[col];
        } else if constexpr (EPI == 1) {
          outF[row * (size_t)ldo + col] += v;
        } else if constexpr (EPI == 3) {
          const float u = v + bias[col];
          outH[row * (size_t)ldo + col] = (f16)(0.5f * u * (1.f + erff(u * 0.70710678118654752f)));
        } else if constexpr (EPI == 4) {
          const int gb = (int)(((size_t)r0 + row) >> 12);  // S = 4096
          const float pre = v + rowterm[((size_t)gb << 10) + col];
          const float gate = 1.f / (1.f + expf(-pre));
          const float ph = (float)phm[row * 1024 + col];
          const bool neg = ph > 2.f;
          const float gs = Gsum[((size_t)gb << 10) + col];
          const float cr = neg ? gs * ratioNeg : 0.f;
          const float ci = gs * (neg ? stNeg : 1.f);
          gr[row * 1024 + col] = (f16)(cr * gate);
          gi[row * 1024 + col] = (f16)(ci * gate);
        } else {  // EPI == 5
          outH[row * (size_t)ldo + col] = (f16)v;
        }
      }
    }
  }
}

extern "C" void kernel_launch(void* const* d_in, const int* in_sizes, int n_in,
                              void* d_out, int out_size, void* d_ws, size_t ws_size,
                              hipStream_t stream) {
  const float* x     = (const float*)d_in[0];
  const float* Wa    = (const float*)d_in[1];
  const float* ba    = (const float*)d_in[2];
  const float* Wp    = (const float*)d_in[3];
  const float* bp    = (const float*)d_in[4];
  const float* gbias = (const float*)d_in[5];
  const float* w1r   = (const float*)d_in[6];
  const float* b1r   = (const float*)d_in[7];
  const float* w2r   = (const float*)d_in[8];
  const float* b2r   = (const float*)d_in[9];
  const float* w1i   = (const float*)d_in[10];
  const float* b1i   = (const float*)d_in[11];
  const float* w2i   = (const float*)d_in[12];
  const float* b2i   = (const float*)d_in[13];
  const float* We    = (const float*)d_in[14];
  const float* be    = (const float*)d_in[15];
  const float* grms  = (const float*)d_in[16];
  const float* wf1   = (const float*)d_in[17];
  const float* bf1   = (const float*)d_in[18];
  const float* wf2   = (const float*)d_in[19];
  const float* bf2   = (const float*)d_in[20];
  float* out = (float*)d_out;

  char* ws = (char*)d_ws;
  size_t off = 0;
  auto alloc = [&](size_t bytes) -> void* {
    void* p = (void*)(ws + off);
    off += (bytes + 255) & ~(size_t)255;
    return p;
  };

  // persistent across the whole launch
  f16* WpT   = (f16*)alloc((size_t)1024 * 1024 * 2);
  f16* w1rT  = (f16*)alloc((size_t)4096 * 1024 * 2);
  f16* w1iT  = (f16*)alloc((size_t)4096 * 1024 * 2);
  f16* wf1T  = (f16*)alloc((size_t)2048 * 1024 * 2);
  f16* wf2T  = (f16*)alloc((size_t)1024 * 2048 * 2);
  f16* WcrT  = (f16*)alloc((size_t)1024 * 4096 * 2);  // [n][k] (w2r@We_top)^T
  f16* WciT  = (f16*)alloc((size_t)1024 * 4096 * 2);  // [n][k] (w2i@We_bot)^T
  float* part    = (float*)alloc((size_t)4 * 16 * 1024 * 4);
  float* GsumB   = (float*)alloc((size_t)4 * 1024 * 4);
  float* ampB    = (float*)alloc((size_t)4 * 1024 * 4);
  float* rowterm = (float*)alloc((size_t)4 * 1024 * 4);
  float* bcB     = (float*)alloc((size_t)1024 * 4);
  const size_t staticEnd = off;

  // temporaries for the Wc precompute, overlapping the chunk region (dead before
  // any chunk kernel writes there; stream ordering guarantees sequencing)
  char* tmp = ws + staticEnd;
  f16* WeT  = (f16*)tmp;                                   // [1024][2048], 4 MB
  f16* w2rH = (f16*)(tmp + (size_t)4 * 1024 * 1024);       // f16 cast, 8 MB
  f16* w2iH = (f16*)(tmp + (size_t)12 * 1024 * 1024);      // f16 cast, 8 MB

  {  // weight transposes + f16 casts (grid = (N/32, K/32) for W[K,N])
    dim3 b(32, 8);
    wtr_k<<<dim3(32, 32), b, 0, stream>>>(Wp, WpT, 1024, 1024);
    wtr_k<<<dim3(128, 32), b, 0, stream>>>(w1r, w1rT, 1024, 4096);
    wtr_k<<<dim3(128, 32), b, 0, stream>>>(w1i, w1iT, 1024, 4096);
    wtr_k<<<dim3(64, 32), b, 0, stream>>>(wf1, wf1T, 1024, 2048);
    wtr_k<<<dim3(32, 64), b, 0, stream>>>(wf2, wf2T, 2048, 1024);
    wtr_k<<<dim3(32, 64), b, 0, stream>>>(We, WeT, 2048, 1024);
    cast_k<<<dim3(4096), 256, 0, stream>>>(w2r, w2rH);
    cast_k<<<dim3(4096), 256, 0, stream>>>(w2i, w2iH);
  }

  colsq_k<<<dim3(4, 16, 4), 256, 0, stream>>>(x, part);
  stats_k<<<4, 256, 0, stream>>>(part, GsumB, ampB);
  rowterm_k<<<dim3(4, 4), 256, 0, stream>>>(ampB, Wa, ba, bp, gbias, rowterm);
  bc_k<<<dim3(4), 256, 0, stream>>>(b2r, b2i, We, be, bcB);

  // WcrT[m][n'] = (w2r@We_top)[n',m] ; WciT[m][n'] = (w2i@We_bot)[n',m]
  gemm2_k<5, 0><<<dim3(8, 16), 512, 0, stream>>>(WeT, 2048, w2rH, 1024, 1024, nullptr,
      nullptr, WcrT, 4096, nullptr, nullptr, nullptr, nullptr, nullptr, 0, 0.f, 0.f);
  gemm2_k<5, 0><<<dim3(8, 16), 512, 0, stream>>>(WeT + 1024, 2048, w2iH, 1024, 1024, nullptr,
      nullptr, WciT, 4096, nullptr, nullptr, nullptr, nullptr, nullptr, 0, 0.f, 0.f);

  // wave_repr collapses: ratio = (x<0 ? -0.99 : 0), sqrt_term = (x<0 ? sqrt(1-.99^2) : 1)
  const float ratioNeg = -0.99f;
  const float stNeg = sqrtf(fmaxf(1.0f - 0.99f * 0.99f, EPSF));
  const float phPos = atan2f(1.0f, 0.0f);
  const float phNeg = atan2f(stNeg, ratioNeg);

  const long Ntok = (long)in_sizes[0] / 1024;  // 16384
  // perRow layout: ph 2K | gr 2K | gi 2K | h1 8K ; waveF overlays ph+gr (4K),
  // outB overlays gi, h2 overlays h1 -> 14336 B/row
  const size_t perRow = 14336;
  long R = (long)((ws_size > staticEnd ? ws_size - staticEnd : 0) / perRow);
  R &= ~255L;
  if (R > Ntok) R = Ntok;
  if (R < 256) R = 256;

  char* cb = ws + staticEnd;
  f16* phB = (f16*)cb;                               // R x 1024
  f16* grB = (f16*)(cb + (size_t)R * 2048);          // R x 1024
  f16* giB = (f16*)(cb + (size_t)R * 4096);          // R x 1024
  f16* h1B = (f16*)(cb + (size_t)R * 6144);          // R x 4096 (r / i sequentially)
  float* waveF = (float*)phB;                        // R x 1024 f32 (ph+gr dead)
  f16* outB = giB;                                   // R x 1024 (gi dead after up-i)
  f16* h2B = h1B;                                    // R x 2048 (h1 dead after down-i)

  for (long r0 = 0; r0 < Ntok; r0 += R) {
    const long Rc = (Ntok - r0 < R) ? (Ntok - r0) : R;
    const int gm = (int)(Rc / 128);
    ph_k<<<dim3((int)Rc), 256, 0, stream>>>(x + r0 * 1024, phB, phPos, phNeg);
    // gate: pre = ph@Wp + rowterm; gr/gi = (cr/ci)*sigmoid(pre)
    gemm2_k<4, 1><<<dim3(gm, 4), 512, 0, stream>>>(phB, 1024, WpT, 1024, 1024, nullptr,
        nullptr, nullptr, 1024, phB, rowterm, GsumB, grB, giB, (int)r0, ratioNeg, stNeg);
    // real half: up -> gelu -> h1 ; wave = h1 @ WcrT^T + bc  (waveF overlays ph+gr)
    gemm2_k<3, 0><<<dim3(gm, 16), 512, 0, stream>>>(grB, 1024, w1rT, 1024, 1024, b1r,
        nullptr, h1B, 4096, nullptr, nullptr, nullptr, nullptr, nullptr, 0, 0.f, 0.f);
    gemm2_k<0, 1><<<dim3(gm, 4), 512, 0, stream>>>(h1B, 4096, WcrT, 4096, 4096, bcB,
        waveF, nullptr, 1024, nullptr, nullptr, nullptr, nullptr, nullptr, 0, 0.f, 0.f);
    // imag half: up -> gelu -> h1 ; wave += h1 @ WciT^T
    gemm2_k<3, 0><<<dim3(gm, 16), 512, 0, stream>>>(giB, 1024, w1iT, 1024, 1024, b1i,
        nullptr, h1B, 4096, nullptr, nullptr, nullptr, nullptr, nullptr, 0, 0.f, 0.f);
    gemm2_k<1, 1><<<dim3(gm, 4), 512, 0, stream>>>(h1B, 4096, WciT, 4096, 4096, nullptr,
        waveF, nullptr, 1024, nullptr, nullptr, nullptr, nullptr, nullptr, 0, 0.f, 0.f);
    rms_k<<<dim3((int)Rc), 256, 0, stream>>>(waveF, grms, outB);
    // block FFN
    gemm2_k<3, 1><<<dim3(gm, 8), 512, 0, stream>>>(outB, 1024, wf1T, 1024, 1024, bf1,
        nullptr, h2B, 2048, nullptr, nullptr, nullptr, nullptr, nullptr, 0, 0.f, 0.f);
    gemm2_k<0, 1><<<dim3(gm, 4), 512, 0, stream>>>(h2B, 2048, wf2T, 2048, 2048, bf2,
        out + r0 * 1024, nullptr, 1024, nullptr, nullptr, nullptr, nullptr, nullptr, 0, 0.f, 0.f);
  }
}

// Round 6
// 1367.830 us; speedup vs baseline: 1.2685x; 1.2258x over previous
//
#include <hip/hip_runtime.h>
#include <cmath>

typedef _Float16 f16;
typedef _Float16 f16x8 __attribute__((ext_vector_type(8)));
typedef _Float16 f16x4 __attribute__((ext_vector_type(4)));
typedef float f32x4 __attribute__((ext_vector_type(4)));

#define EPSF 1e-6f

// ---------------- async global->LDS, 16B per lane ----------------
__device__ __forceinline__ void gload16(const f16* g, const f16* l) {
  __builtin_amdgcn_global_load_lds(
      (__attribute__((address_space(1))) void*)g,
      (__attribute__((address_space(3))) void*)l, 16, 0, 0);
}

// ---------------- fast exact-GELU via A&S 7.1.26 erf (|err| <= 1.5e-7) --------
__device__ __forceinline__ float fast_gelu(float u) {
  const float z = u * 0.70710678118654752f;
  const float az = fabsf(z);
  const float t = __builtin_amdgcn_rcpf(fmaf(0.3275911f, az, 1.0f));
  float p = 1.061405429f;
  p = fmaf(p, t, -1.453152027f);
  p = fmaf(p, t, 1.421413741f);
  p = fmaf(p, t, -0.284496736f);
  p = fmaf(p, t, 0.254829592f);
  p = p * t;
  const float e = __expf(-az * az);
  float er = fmaf(-p, e, 1.0f);      // erf(|z|)
  er = copysignf(er, z);
  return 0.5f * u * (1.0f + er);
}

// ---------------- weight transpose fp32[K,N] -> f16[N,K] ----------------
__global__ void wtr_k(const float* __restrict__ W, f16* __restrict__ WT, int K, int N) {
  __shared__ float t[32][33];
  const int nb = blockIdx.x * 32, kb = blockIdx.y * 32;
  const int tx = threadIdx.x, ty = threadIdx.y;
#pragma unroll
  for (int i = ty; i < 32; i += 8) t[i][tx] = W[(size_t)(kb + i) * N + nb + tx];
  __syncthreads();
#pragma unroll
  for (int i = ty; i < 32; i += 8) WT[(size_t)(nb + i) * K + kb + tx] = (f16)t[tx][i];
}

// ---------------- flat fp32 -> f16 cast ----------------
__global__ void cast_k(const float* __restrict__ W, f16* __restrict__ H) {
  const size_t i = (size_t)blockIdx.x * 256 + threadIdx.x;
  const float4 v = ((const float4*)W)[i];
  f16x4 o;
  o[0] = (f16)v.x; o[1] = (f16)v.y; o[2] = (f16)v.z; o[3] = (f16)v.w;
  ((f16x4*)H)[i] = o;
}

// ---------------- per-(b,sblk,d) partial sum of clipped x^2 ----------------
__global__ void colsq_k(const float* __restrict__ x, float* __restrict__ part) {
  const int d = blockIdx.x * 256 + threadIdx.x;
  const int sb = blockIdx.y;
  const int b = blockIdx.z;
  const float* p = x + ((size_t)b * 4096 + (size_t)sb * 256) * 1024 + d;
  float acc = 0.f;
#pragma unroll 4
  for (int s = 0; s < 256; ++s) {
    float v = p[(size_t)s * 1024];
    v = fminf(fmaxf(v, -10.f), 10.f);
    acc = fmaf(v, v, acc);
  }
  part[((size_t)b * 16 + sb) * 1024 + d] = acc;
}

// ---------------- Gs, Gt -> Gsum, amp per (b,d) ----------------
__global__ void stats_k(const float* __restrict__ part, float* __restrict__ Gsum,
                        float* __restrict__ amp) {
  const int b = blockIdx.x;
  const int t = threadIdx.x;
  __shared__ double red[256];
  float cs[4];
  double tot = 0.0;
#pragma unroll
  for (int i = 0; i < 4; ++i) {
    const int d = t + i * 256;
    double s = 0.0;
    for (int k = 0; k < 16; ++k) s += (double)part[((size_t)b * 16 + k) * 1024 + d];
    cs[i] = (float)s;
    tot += s;
  }
  red[t] = tot;
  __syncthreads();
  for (int st = 128; st > 0; st >>= 1) {
    if (t < st) red[t] += red[t + st];
    __syncthreads();
  }
  const float Gs = fmaxf(sqrtf((float)red[0] + EPSF), EPSF);
#pragma unroll
  for (int i = 0; i < 4; ++i) {
    const int d = t + i * 256;
    const float Gt = fmaxf(sqrtf(cs[i] + EPSF), EPSF);
    const float gs = Gs + Gt;
    Gsum[(b << 10) + d] = gs;
    amp[(b << 10) + d] = sqrtf(gs * gs + EPSF);
  }
}

// ---------------- rowterm[b,d] = amp[b,:]@Wa[:,d] + ba + bp + gate_bias ----------------
__global__ void rowterm_k(const float* __restrict__ amp, const float* __restrict__ Wa,
                          const float* __restrict__ ba, const float* __restrict__ bp,
                          const float* __restrict__ gbias, float* __restrict__ rt) {
  const int b = blockIdx.y;
  const int d = blockIdx.x * 256 + threadIdx.x;
  const float* a = amp + (b << 10);
  double acc = 0.0;
  for (int k = 0; k < 1024; ++k) acc += (double)a[k] * (double)Wa[((size_t)k << 10) + d];
  rt[(b << 10) + d] = (float)acc + ba[d] + bp[d] + gbias[d];
}

// ---------------- combined bias: bc = b2r@We_top + b2i@We_bot + be ----------------
__global__ void bc_k(const float* __restrict__ b2r, const float* __restrict__ b2i,
                     const float* __restrict__ We, const float* __restrict__ be,
                     float* __restrict__ bc) {
  const int n = blockIdx.x * 256 + threadIdx.x;
  double a = 0.0;
  for (int j = 0; j < 1024; ++j) a += (double)b2r[j] * (double)We[(size_t)j * 1024 + n];
  for (int j = 0; j < 1024; ++j)
    a += (double)b2i[j] * (double)We[(size_t)(1024 + j) * 1024 + n];
  bc[n] = (float)a + be[n];
}

// ---------------- ph materialization: two-valued by sign(x) ----------------
__global__ void ph_k(const float* __restrict__ x, f16* __restrict__ ph, float phPos,
                     float phNeg) {
  const size_t i = (size_t)blockIdx.x * 256 + threadIdx.x;
  const float4 v = ((const float4*)x)[i];
  f16x4 o;
  o[0] = (f16)(v.x < 0.f ? phNeg : phPos);
  o[1] = (f16)(v.y < 0.f ? phNeg : phPos);
  o[2] = (f16)(v.z < 0.f ? phNeg : phPos);
  o[3] = (f16)(v.w < 0.f ? phNeg : phPos);
  ((f16x4*)ph)[i] = o;
}

// ---------------- RMSNorm row kernel: f32 in -> f16 out ----------------
__global__ void rms_k(const float* __restrict__ wave, const float* __restrict__ g,
                      f16* __restrict__ o) {
  const size_t row = blockIdx.x;
  const int t = threadIdx.x;
  const float4 v = ((const float4*)(wave + row * 1024))[t];
  float ss = v.x * v.x + v.y * v.y + v.z * v.z + v.w * v.w;
#pragma unroll
  for (int s = 32; s > 0; s >>= 1) ss += __shfl_down(ss, s);
  __shared__ float red[4];
  if ((t & 63) == 0) red[t >> 6] = ss;
  __syncthreads();
  const float tot = red[0] + red[1] + red[2] + red[3];
  const float r = rsqrtf(tot * (1.f / 1024.f) + EPSF);
  const float4 gv = ((const float4*)g)[t];
  f16x4 ov;
  ov[0] = (f16)(v.x * r * gv.x);
  ov[1] = (f16)(v.y * r * gv.y);
  ov[2] = (f16)(v.z * r * gv.z);
  ov[3] = (f16)(v.w * r * gv.w);
  ((f16x4*)(o + row * 1024))[t] = ov;
}

// ======== MFMA GEMM, BM=128 x BN=256, 8 waves (each 64x64 out) ========
// C[M,N] = A[M,K] * BT[N,K]^T.  2-phase dbuf, gload_lds staging, XOR k-slot
// swizzle (conflict-free, rule 21).  Row-outer flatten + bijective XCD chunk
// swizzle: the col-tiles sharing an A band land on one XCD (A band L2-hot).
// f16 outputs (EPI 3/5) staged through wave-private LDS -> f16x8 64B-segment
// stores (kills partial-line write RMW).
// EPI: 0 = +bias -> f32 ; 1 = += -> f32 ; 3 = gelu(+bias) -> f16 ;
//      4 = gate -> gr,gi f16 ; 5 = plain -> f16
template <int EPI>
__global__ __launch_bounds__(512, 4) void gemm2_k(
    const f16* __restrict__ A, int lda, const f16* __restrict__ BT, int ldb, int K,
    const float* __restrict__ bias, float* __restrict__ outF, f16* __restrict__ outH,
    int ldo, const f16* __restrict__ phm, const float* __restrict__ rowterm,
    const float* __restrict__ Gsum, f16* __restrict__ gr, f16* __restrict__ gi, int r0,
    float ratioNeg, float stNeg) {
  __shared__ __align__(16) char smem[49152];
  f16(*smA)[4096] = reinterpret_cast<f16(*)[4096]>(smem);           // [2][4096]
  f16(*smB)[8192] = reinterpret_cast<f16(*)[8192]>(smem + 16384);   // [2][8192]
  const int tid = threadIdx.x;
  const int w = tid >> 6, l = tid & 63;

  // row-outer flatten + bijective XCD-chunk swizzle (m204)
  const int ncol = gridDim.y;
  const int bid = blockIdx.x * ncol + blockIdx.y;
  const int nwg = gridDim.x * ncol;
  const int q = nwg >> 3, rr = nwg & 7;
  const int xcd = bid & 7, idx = bid >> 3;
  const int swz = (xcd < rr ? xcd * (q + 1) : rr * (q + 1) + (xcd - rr) * q) + idx;
  const int bx = swz / ncol, by = swz % ncol;
  const size_t rbase = (size_t)bx * 128;
  const size_t cbase = (size_t)by * 256;

  // staging map: thread covers row srow (A) / srow+128 (B hi half), 16B slot l&3;
  // global k-slot XOR-swizzled by row, LDS linear (rule 21)
  const int srow = (w << 4) + (l >> 2);
  const int slot = l & 3;
  const int ssA = ((slot ^ ((srow >> 1) & 3)) << 3);

  f32x4 acc[4][4];
  const f32x4 zero = {0.f, 0.f, 0.f, 0.f};
#pragma unroll
  for (int m = 0; m < 4; ++m)
#pragma unroll
    for (int n = 0; n < 4; ++n) acc[m][n] = zero;

  const f16* gA = A + (rbase + srow) * (size_t)lda + ssA;
  const f16* gB0 = BT + (cbase + srow) * (size_t)ldb + ssA;
  const int srow1 = srow + 128;
  const f16* gB1 = BT + (cbase + srow1) * (size_t)ldb + ((slot ^ ((srow1 >> 1) & 3)) << 3);

  const int nk = K >> 5;
  auto stage = [&](int buf, size_t ko) {
    gload16(gA + ko, &smA[buf][w << 9]);
    gload16(gB0 + ko, &smB[buf][w << 9]);
    gload16(gB1 + ko, &smB[buf][4096 + (w << 9)]);
  };
  stage(0, 0);
  __syncthreads();

  const int arow = l & 15;
  const int kg = (((l >> 4) ^ ((arow >> 1) & 3)) << 3);  // read-side XOR
  const int wr = (w >> 2) << 6;  // 0 / 64
  const int wc = (w & 3) << 6;   // 0 / 64 / 128 / 192

  for (int t = 0; t < nk; ++t) {
    const int cur = t & 1;
    if (t + 1 < nk) stage(cur ^ 1, (size_t)(t + 1) << 5);
    const f16* ap = &smA[cur][(wr + arow) * 32 + kg];
    const f16* bp = &smB[cur][(wc + arow) * 32 + kg];
    f16x8 af[4], bf[4];
#pragma unroll
    for (int m = 0; m < 4; ++m) af[m] = *(const f16x8*)(ap + m * 512);
#pragma unroll
    for (int n = 0; n < 4; ++n) bf[n] = *(const f16x8*)(bp + n * 512);
#pragma unroll
    for (int m = 0; m < 4; ++m)
#pragma unroll
      for (int n = 0; n < 4; ++n)
        acc[m][n] = __builtin_amdgcn_mfma_f32_16x16x32_f16(af[m], bf[n], acc[m][n], 0, 0, 0);
    __syncthreads();
  }

  // epilogue; C/D layout: col = lane&15, row = (lane>>4)*4 + j
  const int fr = l & 15, hi = l >> 4;
  const int r4 = hi << 2;

  if constexpr (EPI == 3 || EPI == 5) {
    // wave-private LDS C-staging: [16 rows][68 f32] (padded), then f16x8 stores
    float* ep = reinterpret_cast<float*>(smem + w * 4352);
#pragma unroll
    for (int m = 0; m < 4; ++m) {
#pragma unroll
      for (int n = 0; n < 4; ++n) {
        const int cl = n * 16 + fr;
#pragma unroll
        for (int j = 0; j < 4; ++j) {
          float v = acc[m][n][j];
          if constexpr (EPI == 3) v = fast_gelu(v + bias[cbase + wc + cl]);
          ep[(r4 + j) * 68 + cl] = v;
        }
      }
      asm volatile("s_waitcnt lgkmcnt(0)" ::: "memory");
      __builtin_amdgcn_sched_barrier(0);
#pragma unroll
      for (int it = 0; it < 2; ++it) {
        const int rl = l >> 2;
        const int ch = (l & 3) + it * 4;
        const float* pr = &ep[rl * 68 + ch * 8];
        f16x8 o;
#pragma unroll
        for (int e = 0; e < 8; ++e) o[e] = (f16)pr[e];
        *(f16x8*)&outH[(rbase + wr + m * 16 + rl) * (size_t)ldo + (cbase + wc + ch * 8)] = o;
      }
      asm volatile("s_waitcnt lgkmcnt(0)" ::: "memory");
      __builtin_amdgcn_sched_barrier(0);
    }
  } else {
#pragma unroll
    for (int m = 0; m < 4; ++m) {
#pragma unroll
      for (int n = 0; n < 4; ++n) {
        const size_t col = cbase + wc + n * 16 + fr;
#pragma unroll
        for (int j = 0; j < 4; ++j) {
          const size_t row = rbase + wr + m * 16 + r4 + j;
          const float v = acc[m][n][j];
          if constexpr (EPI == 0) {
            outF[row * (size_t)ldo + col] = v + bias[col];
          } else if constexpr (EPI == 1) {
            outF[row * (size_t)ldo + col] += v;
          } else if constexpr (EPI == 4) {
            const int gb = (int)(((size_t)r0 + row) >> 12);  // S = 4096
            const float pre = v + rowterm[((size_t)gb << 10) + col];
            const float gate = __builtin_amdgcn_rcpf(1.f + __expf(-pre));
            const float ph = (float)phm[row * 1024 + col];
            const bool neg = ph > 2.f;
            const float gs = Gsum[((size_t)gb << 10) + col];
            const float cr = neg ? gs * ratioNeg : 0.f;
            const float ci = gs * (neg ? stNeg : 1.f);
            gr[row * 1024 + col] = (f16)(cr * gate);
            gi[row * 1024 + col] = (f16)(ci * gate);
          }
        }
      }
    }
  }
}

extern "C" void kernel_launch(void* const* d_in, const int* in_sizes, int n_in,
                              void* d_out, int out_size, void* d_ws, size_t ws_size,
                              hipStream_t stream) {
  const float* x     = (const float*)d_in[0];
  const float* Wa    = (const float*)d_in[1];
  const float* ba    = (const float*)d_in[2];
  const float* Wp    = (const float*)d_in[3];
  const float* bp    = (const float*)d_in[4];
  const float* gbias = (const float*)d_in[5];
  const float* w1r   = (const float*)d_in[6];
  const float* b1r   = (const float*)d_in[7];
  const float* w2r   = (const float*)d_in[8];
  const float* b2r   = (const float*)d_in[9];
  const float* w1i   = (const float*)d_in[10];
  const float* b1i   = (const float*)d_in[11];
  const float* w2i   = (const float*)d_in[12];
  const float* b2i   = (const float*)d_in[13];
  const float* We    = (const float*)d_in[14];
  const float* be    = (const float*)d_in[15];
  const float* grms  = (const float*)d_in[16];
  const float* wf1   = (const float*)d_in[17];
  const float* bf1   = (const float*)d_in[18];
  const float* wf2   = (const float*)d_in[19];
  const float* bf2   = (const float*)d_in[20];
  float* out = (float*)d_out;

  char* ws = (char*)d_ws;
  size_t off = 0;
  auto alloc = [&](size_t bytes) -> void* {
    void* p = (void*)(ws + off);
    off += (bytes + 255) & ~(size_t)255;
    return p;
  };

  // persistent across the whole launch
  f16* WpT   = (f16*)alloc((size_t)1024 * 1024 * 2);
  f16* w1rT  = (f16*)alloc((size_t)4096 * 1024 * 2);
  f16* w1iT  = (f16*)alloc((size_t)4096 * 1024 * 2);
  f16* wf1T  = (f16*)alloc((size_t)2048 * 1024 * 2);
  f16* wf2T  = (f16*)alloc((size_t)1024 * 2048 * 2);
  f16* WcrT  = (f16*)alloc((size_t)1024 * 4096 * 2);  // [n][k] (w2r@We_top)^T
  f16* WciT  = (f16*)alloc((size_t)1024 * 4096 * 2);  // [n][k] (w2i@We_bot)^T
  float* part    = (float*)alloc((size_t)4 * 16 * 1024 * 4);
  float* GsumB   = (float*)alloc((size_t)4 * 1024 * 4);
  float* ampB    = (float*)alloc((size_t)4 * 1024 * 4);
  float* rowterm = (float*)alloc((size_t)4 * 1024 * 4);
  float* bcB     = (float*)alloc((size_t)1024 * 4);
  const size_t staticEnd = off;

  // temporaries for the Wc precompute, overlapping the chunk region (dead before
  // any chunk kernel writes there; stream ordering guarantees sequencing)
  char* tmp = ws + staticEnd;
  f16* WeT  = (f16*)tmp;                                   // [1024][2048], 4 MB
  f16* w2rH = (f16*)(tmp + (size_t)4 * 1024 * 1024);       // f16 cast, 8 MB
  f16* w2iH = (f16*)(tmp + (size_t)12 * 1024 * 1024);      // f16 cast, 8 MB

  {  // weight transposes + f16 casts (grid = (N/32, K/32) for W[K,N])
    dim3 b(32, 8);
    wtr_k<<<dim3(32, 32), b, 0, stream>>>(Wp, WpT, 1024, 1024);
    wtr_k<<<dim3(128, 32), b, 0, stream>>>(w1r, w1rT, 1024, 4096);
    wtr_k<<<dim3(128, 32), b, 0, stream>>>(w1i, w1iT, 1024, 4096);
    wtr_k<<<dim3(64, 32), b, 0, stream>>>(wf1, wf1T, 1024, 2048);
    wtr_k<<<dim3(32, 64), b, 0, stream>>>(wf2, wf2T, 2048, 1024);
    wtr_k<<<dim3(32, 64), b, 0, stream>>>(We, WeT, 2048, 1024);
    cast_k<<<dim3(4096), 256, 0, stream>>>(w2r, w2rH);
    cast_k<<<dim3(4096), 256, 0, stream>>>(w2i, w2iH);
  }

  colsq_k<<<dim3(4, 16, 4), 256, 0, stream>>>(x, part);
  stats_k<<<4, 256, 0, stream>>>(part, GsumB, ampB);
  rowterm_k<<<dim3(4, 4), 256, 0, stream>>>(ampB, Wa, ba, bp, gbias, rowterm);
  bc_k<<<dim3(4), 256, 0, stream>>>(b2r, b2i, We, be, bcB);

  // WcrT[m][n'] = (w2r@We_top)[n',m] ; WciT[m][n'] = (w2i@We_bot)[n',m]
  gemm2_k<5><<<dim3(8, 16), 512, 0, stream>>>(WeT, 2048, w2rH, 1024, 1024, nullptr,
      nullptr, WcrT, 4096, nullptr, nullptr, nullptr, nullptr, nullptr, 0, 0.f, 0.f);
  gemm2_k<5><<<dim3(8, 16), 512, 0, stream>>>(WeT + 1024, 2048, w2iH, 1024, 1024, nullptr,
      nullptr, WciT, 4096, nullptr, nullptr, nullptr, nullptr, nullptr, 0, 0.f, 0.f);

  // wave_repr collapses: ratio = (x<0 ? -0.99 : 0), sqrt_term = (x<0 ? sqrt(1-.99^2) : 1)
  const float ratioNeg = -0.99f;
  const float stNeg = sqrtf(fmaxf(1.0f - 0.99f * 0.99f, EPSF));
  const float phPos = atan2f(1.0f, 0.0f);
  const float phNeg = atan2f(stNeg, ratioNeg);

  const long Ntok = (long)in_sizes[0] / 1024;  // 16384
  // perRow layout: ph 2K | gr 2K | gi 2K | h1 8K ; waveF overlays ph+gr (4K),
  // outB overlays gi, h2 overlays h1 -> 14336 B/row.  Cap R at 8192 so the h1
  // round-trip (64 MB) stays L3-resident.
  const size_t perRow = 14336;
  long R = (long)((ws_size > staticEnd ? ws_size - staticEnd : 0) / perRow);
  R &= ~255L;
  if (R > 8192) R = 8192;
  if (R < 256) R = 256;

  char* cb = ws + staticEnd;
  f16* phB = (f16*)cb;                               // R x 1024
  f16* grB = (f16*)(cb + (size_t)R * 2048);          // R x 1024
  f16* giB = (f16*)(cb + (size_t)R * 4096);          // R x 1024
  f16* h1B = (f16*)(cb + (size_t)R * 6144);          // R x 4096 (r / i sequentially)
  float* waveF = (float*)phB;                        // R x 1024 f32 (ph+gr dead)
  f16* outB = giB;                                   // R x 1024 (gi dead after up-i)
  f16* h2B = h1B;                                    // R x 2048 (h1 dead after down-i)

  for (long r0 = 0; r0 < Ntok; r0 += R) {
    const long Rc = (Ntok - r0 < R) ? (Ntok - r0) : R;
    const int gm = (int)(Rc / 128);
    ph_k<<<dim3((int)Rc), 256, 0, stream>>>(x + r0 * 1024, phB, phPos, phNeg);
    // gate: pre = ph@Wp + rowterm; gr/gi = (cr/ci)*sigmoid(pre)
    gemm2_k<4><<<dim3(gm, 4), 512, 0, stream>>>(phB, 1024, WpT, 1024, 1024, nullptr,
        nullptr, nullptr, 1024, phB, rowterm, GsumB, grB, giB, (int)r0, ratioNeg, stNeg);
    // real half: up -> gelu -> h1 ; wave = h1 @ WcrT^T + bc  (waveF overlays ph+gr)
    gemm2_k<3><<<dim3(gm, 16), 512, 0, stream>>>(grB, 1024, w1rT, 1024, 1024, b1r,
        nullptr, h1B, 4096, nullptr, nullptr, nullptr, nullptr, nullptr, 0, 0.f, 0.f);
    gemm2_k<0><<<dim3(gm, 4), 512, 0, stream>>>(h1B, 4096, WcrT, 4096, 4096, bcB,
        waveF, nullptr, 1024, nullptr, nullptr, nullptr, nullptr, nullptr, 0, 0.f, 0.f);
    // imag half: up -> gelu -> h1 ; wave += h1 @ WciT^T
    gemm2_k<3><<<dim3(gm, 16), 512, 0, stream>>>(giB, 1024, w1iT, 1024, 1024, b1i,
        nullptr, h1B, 4096, nullptr, nullptr, nullptr, nullptr, nullptr, 0, 0.f, 0.f);
    gemm2_k<1><<<dim3(gm, 4), 512, 0, stream>>>(h1B, 4096, WciT, 4096, 4096, nullptr,
        waveF, nullptr, 1024, nullptr, nullptr, nullptr, nullptr, nullptr, 0, 0.f, 0.f);
    rms_k<<<dim3((int)Rc), 256, 0, stream>>>(waveF, grms, outB);
    // block FFN
    gemm2_k<3><<<dim3(gm, 8), 512, 0, stream>>>(outB, 1024, wf1T, 1024, 1024, bf1,
        nullptr, h2B, 2048, nullptr, nullptr, nullptr, nullptr, nullptr, 0, 0.f, 0.f);
    gemm2_k<0><<<dim3(gm, 4), 512, 0, stream>>>(h2B, 2048, wf2T, 2048, 2048, bf2,
        out + r0 * 1024, nullptr, 1024, nullptr, nullptr, nullptr, nullptr, nullptr, 0, 0.f, 0.f);
  }
}